// Round 3
// baseline (284.942 us; speedup 1.0000x reference)
//
#include <hip/hip_runtime.h>
#include <hip/hip_bf16.h>
#include <hip/hip_cooperative_groups.h>

namespace cg = cooperative_groups;

#define HH 512
#define WW 512
#define NJ 250
#define NBINS 8192
#define NPAIR 31125   // 250*249/2
#define NBLK 256
#define NTHR 256
#define NTOT (NBLK * NTHR)
#define NWAVE (NTOT / 64)

// Patch offsets sorted by ascending radius^2 (0,1,2,4,5,8,9) — 29 entries.
__device__ __constant__ float POH[29] = {
    0,  0, 0, 1,-1,  1, 1,-1,-1,  0, 0, 2,-2,
    1, 1,-1,-1, 2, 2,-2,-2,  2, 2,-2,-2,  0, 0, 3,-3
};
__device__ __constant__ float POW[29] = {
    0,  1,-1, 0, 0,  1,-1, 1,-1,  2,-2, 0, 0,
    2,-2, 2,-2, 1,-1, 1,-1,  2,-2, 2,-2,  3,-3, 0, 0
};

__global__ __launch_bounds__(NTHR) void coop_kernel(
    const float* __restrict__ junc, const float* __restrict__ hm,
    float* __restrict__ out_lm, float* __restrict__ out_junc,
    float* __restrict__ out_hm, unsigned* __restrict__ ws_u) {
    cg::grid_group grid = cg::this_grid();

    unsigned* cnt   = ws_u;                          // 8192
    float*    sm    = (float*)(ws_u + NBINS);        // 8192
    unsigned* vc    = ws_u + 2 * NBINS;              // 1
    float*    max20 = (float*)(ws_u + 2 * NBINS + 1);// 1

    __shared__ unsigned sc[256];
    __shared__ double   ss[256];
    __shared__ float    sj[2 * NJ];

    const int tid  = blockIdx.x * NTHR + threadIdx.x;
    const int lane = threadIdx.x & 63;

    // ---- P0: zero workspace (hist cnt+sum, valid count, max20)
    for (int i = tid; i < 2 * NBINS + 2; i += NTOT) ws_u[i] = 0;
    grid.sync();

    // ---- P1: histogram of valid heatmap values (float4 loads)
    {
        const float4* hm4 = (const float4*)hm;
        unsigned lv = 0;
        for (int i = tid; i < HH * WW / 4; i += NTOT) {
            float4 v4 = hm4[i];
            float vv[4] = {v4.x, v4.y, v4.z, v4.w};
#pragma unroll
            for (int q = 0; q < 4; ++q) {
                float v = vv[q];
                if (v > 0.001f) {
                    lv++;
                    int b = (int)(v * (float)NBINS);
                    b = min(max(b, 0), NBINS - 1);
                    atomicAdd(&cnt[b], 1u);
                    atomicAdd(&sm[b], v);
                }
            }
        }
        for (int off = 32; off; off >>= 1) lv += __shfl_down(lv, off);
        if (lane == 0) atomicAdd(vc, lv);
    }
    grid.sync();

    // ---- P2: block 0 finds top-k boundary -> max20
    if (blockIdx.x == 0) {
        int t = threadIdx.x;
        unsigned pc = 0;
        double ps = 0.0;
        for (int j = 0; j < 32; ++j) {
            int b = (NBINS - 1) - (t * 32 + j);
            pc += cnt[b];
            ps += (double)sm[b];
        }
        sc[t] = pc; ss[t] = ps;
        __syncthreads();
        for (int off = 1; off < 256; off <<= 1) {
            unsigned cadd = (t >= off) ? sc[t - off] : 0u;
            double   sadd = (t >= off) ? ss[t - off] : 0.0;
            __syncthreads();
            sc[t] += cadd; ss[t] += sadd;
            __syncthreads();
        }
        unsigned incl_c = sc[t];
        double   incl_s = ss[t];
        unsigned excl_c = incl_c - pc;
        double   excl_s = incl_s - ps;

        unsigned C = *vc;
        int k = (int)ceilf((float)C * 0.2f);   // replicate jnp f32 arithmetic
        if (k > 0 && excl_c < (unsigned)k && incl_c >= (unsigned)k) {
            unsigned cum = excl_c;
            double s = excl_s;
            for (int j = 0; j < 32; ++j) {
                int b = (NBINS - 1) - (t * 32 + j);
                unsigned cb = cnt[b];
                if (cum + cb >= (unsigned)k) {
                    unsigned r = (unsigned)k - cum;
                    double partial = cb ? (double)sm[b] * ((double)r / (double)cb) : 0.0;
                    *max20 = (float)((s + partial) / (double)k);
                    break;
                }
                cum += cb;
                s += (double)sm[b];
            }
        }
    }
    grid.sync();

    const float m = *max20;

    // ---- P3: write outputs (refined heatmap, junctions, zeroed line_map)
    {
        const float4* h4 = (const float4*)hm;
        float4* o4 = (float4*)out_hm;
        for (int i = tid; i < HH * WW / 4; i += NTOT) {
            float4 v = h4[i];
            float4 r;
            r.x = fminf(fmaxf(v.x / m, 0.0f), 1.0f);
            r.y = fminf(fmaxf(v.y / m, 0.0f), 1.0f);
            r.z = fminf(fmaxf(v.z / m, 0.0f), 1.0f);
            r.w = fminf(fmaxf(v.w / m, 0.0f), 1.0f);
            o4[i] = r;
        }
        for (int i = tid; i < NJ * NJ; i += NTOT) out_lm[i] = 0.0f;
        if (tid < 2 * NJ) out_junc[tid] = junc[tid];
    }
    // stage junctions in LDS for the pairs phase
    for (int i = threadIdx.x; i < 2 * NJ; i += NTHR) sj[i] = junc[i];
    grid.sync();   // line_map zeroing complete before any 1.0 write

    // ---- P4: persistent pairs loop (one wave per pair)
    const int wave = tid >> 6;
    for (int mm = wave; mm < NPAIR; mm += NWAVE) {
        // decode triangular index: base(i) = i*(499-i)/2
        int i = (int)((499.0 - sqrt(249001.0 - 8.0 * (double)mm)) * 0.5);
        if (i < 0) i = 0;
        while ((i + 1) * (499 - (i + 1)) / 2 <= mm) ++i;
        while (i * (499 - i) / 2 > mm) --i;
        int j = i + 1 + (mm - i * (499 - i) / 2);

        float sh = sj[2 * i], sw = sj[2 * i + 1];
        float eh = sj[2 * j], ew = sj[2 * j + 1];
        float dh = eh - sh, dw = ew - sw;
        float L2 = dh * dh + dw * dw;

        // keep: any other junction on the segment (dist<=3, proj in [0,1])?
        int ck = 0;
        for (int n = lane; n < NJ; n += 64) {
            if (n == i || n == j) continue;
            float vh = sj[2 * n] - sh;
            float vw = sj[2 * n + 1] - sw;
            float dot = vh * dh + vw * dw;
            if (dot >= 0.0f && dot <= L2) {
                float cn2 = vh * vh + vw * vw;
                float dist2 = cn2 - (dot * dot) / L2;
                if (dist2 <= 9.0f) ck++;
            }
        }
        if (__any(ck > 0)) continue;   // suppressed -> not detected

        // per-sample early-exit: lane resolves when a masked refined value > 0.5
        float t = (float)lane / 63.0f;
        float ch = fminf(fmaxf(sh * t + eh * (1.0f - t), 0.0f), (float)(HH - 1));
        float cw = fminf(fmaxf(sw * t + ew * (1.0f - t), 0.0f), (float)(WW - 1));
        float rh = rintf(ch), rw = rintf(cw);
        float fh = ch - rh, fw = cw - rw;
        float L = sqrtf(L2);
        float nl = L / 724.07734f;
        float th = 0.70710678f + 2.0f * nl;
        float th2 = th * th;

        bool need = true;
        for (int p = 0; p < 29; ++p) {
            if (!__any(need)) break;
            if (need) {
                float oh = POH[p], ow = POW[p];
                float ddh = fh - oh, ddw = fw - ow;
                if (ddh * ddh + ddw * ddw < th2) {
                    int ph = (int)fminf(fmaxf(rh + oh, 0.0f), (float)(HH - 1));
                    int pw = (int)fminf(fmaxf(rw + ow, 0.0f), (float)(WW - 1));
                    float v = hm[(ph << 9) + pw];
                    // identical to ref's clip(v/m,0,1) > 0.5
                    if (v / m > 0.5f) need = false;
                }
            }
        }
        if (__any(need)) continue;     // some exact lmax <= 0.5

        if (lane == 0) {
            out_lm[i * NJ + j] = 1.0f;
            out_lm[j * NJ + i] = 1.0f;
        }
    }
}

extern "C" void kernel_launch(void* const* d_in, const int* in_sizes, int n_in,
                              void* d_out, int out_size, void* d_ws, size_t ws_size,
                              hipStream_t stream) {
    const float* junc = (const float*)d_in[0];   // [250,2]
    const float* hm   = (const float*)d_in[1];   // [512,512]
    float* out = (float*)d_out;
    float* out_lm   = out;                      // 62500 floats (0.0/1.0)
    float* out_junc = out + NJ * NJ;            // 500
    float* out_hm   = out + NJ * NJ + 2 * NJ;   // 262144
    unsigned* ws_u  = (unsigned*)d_ws;          // 64 KB + 8 B used

    void* args[] = {(void*)&junc, (void*)&hm, (void*)&out_lm,
                    (void*)&out_junc, (void*)&out_hm, (void*)&ws_u};
    hipLaunchCooperativeKernel((void*)coop_kernel, dim3(NBLK), dim3(NTHR),
                               args, 0, stream);
}

// Round 4
// 174.012 us; speedup vs baseline: 1.6375x; 1.6375x over previous
//
#include <hip/hip_runtime.h>
#include <hip/hip_bf16.h>

#define HH 512
#define WW 512
#define NJ 250
#define NBINS 8192
#define NPAIR 31125   // 250*249/2

#define HBLK 8
#define HTHR 1024
#define STHR 1024
#define CBLK 1024
#define CTHR 256
#define CTOT (CBLK * CTHR)
#define CWAVES (CTOT / 64)

// ---- Kernel A: per-block LDS histogram -> partials in ws (no global atomics,
// ---- no pre-zeroed memory needed)
__global__ __launch_bounds__(HTHR) void hist_kernel(const float* __restrict__ hm,
                                                    unsigned* __restrict__ pcnt,
                                                    float* __restrict__ psum) {
    __shared__ unsigned lc[NBINS];   // 32 KB
    __shared__ float    ls[NBINS];   // 32 KB
    for (int i = threadIdx.x; i < NBINS; i += HTHR) { lc[i] = 0u; ls[i] = 0.0f; }
    __syncthreads();

    const float4* h4 = (const float4*)hm;
    for (int i = blockIdx.x * HTHR + threadIdx.x; i < HH * WW / 4; i += HBLK * HTHR) {
        float4 v4 = h4[i];
        float vv[4] = {v4.x, v4.y, v4.z, v4.w};
#pragma unroll
        for (int q = 0; q < 4; ++q) {
            float v = vv[q];
            if (v > 0.001f) {
                int b = (int)(v * (float)NBINS);
                b = min(max(b, 0), NBINS - 1);
                atomicAdd(&lc[b], 1u);
                atomicAdd(&ls[b], v);
            }
        }
    }
    __syncthreads();
    // partials laid out bin-major for the merge: [bin][block]
    for (int i = threadIdx.x; i < NBINS; i += HTHR) {
        pcnt[i * HBLK + blockIdx.x] = lc[i];
        psum[i * HBLK + blockIdx.x] = ls[i];
    }
}

// ---- Kernel B: merge partials, 1024-wide descending prefix scan, top-k -> max20
__global__ __launch_bounds__(STHR) void select_kernel(const unsigned* __restrict__ pcnt,
                                                      const float* __restrict__ psum,
                                                      float* __restrict__ max20) {
    __shared__ unsigned sc[STHR];
    __shared__ double   ss[STHR];
    const int t = threadIdx.x;

    unsigned mycnt[8];
    double   mysum[8];
    unsigned c = 0;
    double   s = 0.0;
#pragma unroll
    for (int j = 0; j < 8; ++j) {
        int b = (NBINS - 1) - (t * 8 + j);   // descending bins
        unsigned cb = 0;
        double   sb = 0.0;
#pragma unroll
        for (int p = 0; p < HBLK; ++p) {
            cb += pcnt[b * HBLK + p];
            sb += (double)psum[b * HBLK + p];
        }
        mycnt[j] = cb; mysum[j] = sb;
        c += cb; s += sb;
    }
    sc[t] = c; ss[t] = s;
    __syncthreads();
    for (int off = 1; off < STHR; off <<= 1) {
        unsigned ca = (t >= off) ? sc[t - off] : 0u;
        double   sa = (t >= off) ? ss[t - off] : 0.0;
        __syncthreads();
        sc[t] += ca; ss[t] += sa;
        __syncthreads();
    }
    unsigned incl_c = sc[t];
    double   incl_s = ss[t];
    unsigned excl_c = incl_c - c;
    double   excl_s = incl_s - s;

    unsigned C = sc[STHR - 1];              // total valid count
    int k = (int)ceilf((float)C * 0.2f);    // replicate jnp f32 arithmetic
    if (k <= 0) {
        if (t == 0) *max20 = 0.0f;
        return;
    }
    if (excl_c < (unsigned)k && incl_c >= (unsigned)k) {
        unsigned cum = excl_c;
        double sacc = excl_s;
#pragma unroll
        for (int j = 0; j < 8; ++j) {
            unsigned cb = mycnt[j];
            if (cum + cb >= (unsigned)k) {
                unsigned r = (unsigned)k - cum;
                double partial = cb ? mysum[j] * ((double)r / (double)cb) : 0.0;
                *max20 = (float)((sacc + partial) / (double)k);
                break;
            }
            cum += cb;
            sacc += mysum[j];
        }
    }
}

// ---- Kernel C: refine heatmap + copy junctions + full line_map (0/1 writes)
// Patch offsets sorted by ascending radius^2 — 29 entries.
__device__ __constant__ float POH[29] = {
    0,  0, 0, 1,-1,  1, 1,-1,-1,  0, 0, 2,-2,
    1, 1,-1,-1, 2, 2,-2,-2,  2, 2,-2,-2,  0, 0, 3,-3
};
__device__ __constant__ float POW[29] = {
    0,  1,-1, 0, 0,  1,-1, 1,-1,  2,-2, 0, 0,
    2,-2, 2,-2, 1,-1, 1,-1,  2,-2, 2,-2,  3,-3, 0, 0
};

__global__ __launch_bounds__(CTHR) void main_kernel(const float* __restrict__ junc,
                                                    const float* __restrict__ hm,
                                                    const float* __restrict__ max20p,
                                                    float* __restrict__ out_lm,
                                                    float* __restrict__ out_junc,
                                                    float* __restrict__ out_hm) {
    __shared__ float sj[2 * NJ];
    const int tid  = blockIdx.x * CTHR + threadIdx.x;
    const int lane = threadIdx.x & 63;
    const float m = *max20p;

    for (int i = threadIdx.x; i < 2 * NJ; i += CTHR) sj[i] = junc[i];

    // refined heatmap (one float4 per thread for the first 65536 threads)
    if (tid < HH * WW / 4) {
        const float4* h4 = (const float4*)hm;
        float4* o4 = (float4*)out_hm;
        float4 v = h4[tid];
        float4 r;
        r.x = fminf(fmaxf(v.x / m, 0.0f), 1.0f);
        r.y = fminf(fmaxf(v.y / m, 0.0f), 1.0f);
        r.z = fminf(fmaxf(v.z / m, 0.0f), 1.0f);
        r.w = fminf(fmaxf(v.w / m, 0.0f), 1.0f);
        o4[tid] = r;
    }
    if (tid < 2 * NJ) out_junc[tid] = junc[tid];
    if (tid < NJ) out_lm[tid * (NJ + 1)] = 0.0f;   // diagonal
    __syncthreads();

    // persistent pairs loop: one wave per pair; every pair writes both cells
    const int wave = tid >> 6;
    for (int mm = wave; mm < NPAIR; mm += CWAVES) {
        // decode triangular index: base(i) = i*(499-i)/2
        int i = (int)((499.0 - sqrt(249001.0 - 8.0 * (double)mm)) * 0.5);
        if (i < 0) i = 0;
        while ((i + 1) * (499 - (i + 1)) / 2 <= mm) ++i;
        while (i * (499 - i) / 2 > mm) --i;
        int j = i + 1 + (mm - i * (499 - i) / 2);

        float sh = sj[2 * i], sw = sj[2 * i + 1];
        float eh = sj[2 * j], ew = sj[2 * j + 1];
        float dh = eh - sh, dw = ew - sw;
        float L2 = dh * dh + dw * dw;

        // keep: any other junction on the segment (dist<=3, proj in [0,1])?
        int ck = 0;
        for (int n = lane; n < NJ; n += 64) {
            if (n == i || n == j) continue;
            float vh = sj[2 * n] - sh;
            float vw = sj[2 * n + 1] - sw;
            float dot = vh * dh + vw * dw;
            if (dot >= 0.0f && dot <= L2) {
                float cn2 = vh * vh + vw * vw;
                float dist2 = cn2 - (dot * dot) / L2;
                if (dist2 <= 9.0f) ck++;
            }
        }
        bool det = false;
        if (!__any(ck > 0)) {
            // per-sample early-exit: lane resolves when a masked value/m > 0.5
            float t = (float)lane / 63.0f;
            float ch = fminf(fmaxf(sh * t + eh * (1.0f - t), 0.0f), (float)(HH - 1));
            float cw = fminf(fmaxf(sw * t + ew * (1.0f - t), 0.0f), (float)(WW - 1));
            float rh = rintf(ch), rw = rintf(cw);
            float fh = ch - rh, fw = cw - rw;
            float L = sqrtf(L2);
            float nl = L / 724.07734f;
            float th = 0.70710678f + 2.0f * nl;
            float th2 = th * th;

            bool need = true;
            for (int p = 0; p < 29; ++p) {
                if (!__any(need)) break;
                if (need) {
                    float oh = POH[p], ow = POW[p];
                    float ddh = fh - oh, ddw = fw - ow;
                    if (ddh * ddh + ddw * ddw < th2) {
                        int ph = (int)fminf(fmaxf(rh + oh, 0.0f), (float)(HH - 1));
                        int pw = (int)fminf(fmaxf(rw + ow, 0.0f), (float)(WW - 1));
                        // identical to ref's clip(v/m,0,1) > 0.5
                        if (hm[(ph << 9) + pw] / m > 0.5f) need = false;
                    }
                }
            }
            det = !__any(need);   // every lane's exact lmax > 0.5
        }
        if (lane == 0) {
            float val = det ? 1.0f : 0.0f;
            out_lm[i * NJ + j] = val;
            out_lm[j * NJ + i] = val;
        }
    }
}

extern "C" void kernel_launch(void* const* d_in, const int* in_sizes, int n_in,
                              void* d_out, int out_size, void* d_ws, size_t ws_size,
                              hipStream_t stream) {
    const float* junc = (const float*)d_in[0];   // [250,2]
    const float* hm   = (const float*)d_in[1];   // [512,512]
    float* out = (float*)d_out;
    float* out_lm   = out;                      // 62500 floats (0.0/1.0)
    float* out_junc = out + NJ * NJ;            // 500
    float* out_hm   = out + NJ * NJ + 2 * NJ;   // 262144

    unsigned* pcnt  = (unsigned*)d_ws;                           // 8192*8 u32
    float*    psum  = (float*)((char*)d_ws + NBINS * HBLK * 4);  // 8192*8 f32
    float*    max20 = (float*)((char*)d_ws + NBINS * HBLK * 8);  // 1 f32

    hist_kernel<<<HBLK, HTHR, 0, stream>>>(hm, pcnt, psum);
    select_kernel<<<1, STHR, 0, stream>>>(pcnt, psum, max20);
    main_kernel<<<CBLK, CTHR, 0, stream>>>(junc, hm, max20, out_lm, out_junc, out_hm);
}

// Round 5
// 111.990 us; speedup vs baseline: 2.5443x; 1.5538x over previous
//
#include <hip/hip_runtime.h>
#include <hip/hip_bf16.h>

#define HH 512
#define WW 512
#define NJ 250
#define NBINS 8192
#define NPAIR 31125   // 250*249/2

#define H1BLK 64
#define H1THR 1024
#define MBLK 32
#define MTHR 256
#define STHR 1024
#define CBLK 1024
#define CTHR 256
#define CTOT (CBLK * CTHR)
#define CWAVES (CTOT / 64)

// ---- K1: per-block LDS histogram, ONE packed u64 atomic per valid value.
// packet = (1<<40) | round(v * 2^24); count in bits [40..63], sum in [0..39].
// Per-block bin sum <= 4096 * 2^24 < 2^40 -> fields never carry into each other.
__global__ __launch_bounds__(H1THR) void hist_kernel(const float* __restrict__ hm,
                                                     unsigned long long* __restrict__ part) {
    __shared__ unsigned long long h[NBINS];   // 64 KB
    for (int i = threadIdx.x; i < NBINS; i += H1THR) h[i] = 0ull;
    __syncthreads();

    int idx = blockIdx.x * H1THR + threadIdx.x;     // 65536 threads, 1 float4 each
    float4 v4 = ((const float4*)hm)[idx];
    float vv[4] = {v4.x, v4.y, v4.z, v4.w};
#pragma unroll
    for (int q = 0; q < 4; ++q) {
        float v = vv[q];
        if (v > 0.001f) {
            int b = (int)(v * (float)NBINS);
            b = min(max(b, 0), NBINS - 1);
            unsigned long long pkt = (1ull << 40) |
                (unsigned long long)(unsigned)(v * 16777216.0f + 0.5f);
            atomicAdd(&h[b], pkt);
        }
    }
    __syncthreads();
    for (int i = threadIdx.x; i < NBINS; i += H1THR)
        part[blockIdx.x * NBINS + i] = h[i];
}

// ---- K2: merge 64 partials per bin -> u32 cnt + f32 sum (one thread per bin)
__global__ __launch_bounds__(MTHR) void merge_kernel(const unsigned long long* __restrict__ part,
                                                     unsigned* __restrict__ cnt,
                                                     float* __restrict__ sum) {
    int bin = blockIdx.x * MTHR + threadIdx.x;      // 8192 threads
    unsigned c = 0;
    double s = 0.0;
    for (int p = 0; p < H1BLK; ++p) {
        unsigned long long x = part[p * NBINS + bin];
        c += (unsigned)(x >> 40);
        s += (double)(x & ((1ull << 40) - 1));
    }
    cnt[bin] = c;
    sum[bin] = (float)(s * (1.0 / 16777216.0));
}

// ---- K3: descending prefix scan over bins, top-k boundary -> max20
__global__ __launch_bounds__(STHR) void select_kernel(const unsigned* __restrict__ cnt,
                                                      const float* __restrict__ sum,
                                                      float* __restrict__ max20) {
    __shared__ unsigned sc[STHR];
    __shared__ double   ss[STHR];
    const int t = threadIdx.x;

    unsigned mycnt[8];
    double   mysum[8];
    unsigned c = 0;
    double   s = 0.0;
#pragma unroll
    for (int j = 0; j < 8; ++j) {
        int b = (NBINS - 1) - (t * 8 + j);   // descending bins
        unsigned cb = cnt[b];
        double   sb = (double)sum[b];
        mycnt[j] = cb; mysum[j] = sb;
        c += cb; s += sb;
    }
    sc[t] = c; ss[t] = s;
    __syncthreads();
    for (int off = 1; off < STHR; off <<= 1) {
        unsigned ca = (t >= off) ? sc[t - off] : 0u;
        double   sa = (t >= off) ? ss[t - off] : 0.0;
        __syncthreads();
        sc[t] += ca; ss[t] += sa;
        __syncthreads();
    }
    unsigned incl_c = sc[t];
    double   incl_s = ss[t];
    unsigned excl_c = incl_c - c;
    double   excl_s = incl_s - s;

    unsigned C = sc[STHR - 1];              // total valid count
    int k = (int)ceilf((float)C * 0.2f);    // replicate jnp f32 arithmetic
    if (k <= 0) {
        if (t == 0) *max20 = 0.0f;
        return;
    }
    if (excl_c < (unsigned)k && incl_c >= (unsigned)k) {
        unsigned cum = excl_c;
        double sacc = excl_s;
#pragma unroll
        for (int j = 0; j < 8; ++j) {
            unsigned cb = mycnt[j];
            if (cum + cb >= (unsigned)k) {
                unsigned r = (unsigned)k - cum;
                double partial = cb ? mysum[j] * ((double)r / (double)cb) : 0.0;
                *max20 = (float)((sacc + partial) / (double)k);
                break;
            }
            cum += cb;
            sacc += mysum[j];
        }
    }
}

// ---- K4: refine heatmap + copy junctions + full line_map (0/1 writes)
// Patch offsets sorted by ascending radius^2 — 29 entries.
__device__ __constant__ float POH[29] = {
    0,  0, 0, 1,-1,  1, 1,-1,-1,  0, 0, 2,-2,
    1, 1,-1,-1, 2, 2,-2,-2,  2, 2,-2,-2,  0, 0, 3,-3
};
__device__ __constant__ float POW[29] = {
    0,  1,-1, 0, 0,  1,-1, 1,-1,  2,-2, 0, 0,
    2,-2, 2,-2, 1,-1, 1,-1,  2,-2, 2,-2,  3,-3, 0, 0
};

__global__ __launch_bounds__(CTHR) void main_kernel(const float* __restrict__ junc,
                                                    const float* __restrict__ hm,
                                                    const float* __restrict__ max20p,
                                                    float* __restrict__ out_lm,
                                                    float* __restrict__ out_junc,
                                                    float* __restrict__ out_hm) {
    __shared__ float sj[2 * NJ];
    const int tid  = blockIdx.x * CTHR + threadIdx.x;
    const int lane = threadIdx.x & 63;
    const float m = *max20p;

    for (int i = threadIdx.x; i < 2 * NJ; i += CTHR) sj[i] = junc[i];

    // refined heatmap (one float4 per thread for the first 65536 threads)
    if (tid < HH * WW / 4) {
        const float4* h4 = (const float4*)hm;
        float4* o4 = (float4*)out_hm;
        float4 v = h4[tid];
        float4 r;
        r.x = fminf(fmaxf(v.x / m, 0.0f), 1.0f);
        r.y = fminf(fmaxf(v.y / m, 0.0f), 1.0f);
        r.z = fminf(fmaxf(v.z / m, 0.0f), 1.0f);
        r.w = fminf(fmaxf(v.w / m, 0.0f), 1.0f);
        o4[tid] = r;
    }
    if (tid < 2 * NJ) out_junc[tid] = junc[tid];
    if (tid < NJ) out_lm[tid * (NJ + 1)] = 0.0f;   // diagonal
    __syncthreads();

    // persistent pairs loop: one wave per pair; every pair writes both cells
    const int wave = tid >> 6;
    for (int mm = wave; mm < NPAIR; mm += CWAVES) {
        // decode triangular index: base(i) = i*(499-i)/2
        int i = (int)((499.0 - sqrt(249001.0 - 8.0 * (double)mm)) * 0.5);
        if (i < 0) i = 0;
        while ((i + 1) * (499 - (i + 1)) / 2 <= mm) ++i;
        while (i * (499 - i) / 2 > mm) --i;
        int j = i + 1 + (mm - i * (499 - i) / 2);

        float sh = sj[2 * i], sw = sj[2 * i + 1];
        float eh = sj[2 * j], ew = sj[2 * j + 1];
        float dh = eh - sh, dw = ew - sw;
        float L2 = dh * dh + dw * dw;

        // keep: any other junction on the segment (dist<=3, proj in [0,1])?
        int ck = 0;
        for (int n = lane; n < NJ; n += 64) {
            if (n == i || n == j) continue;
            float vh = sj[2 * n] - sh;
            float vw = sj[2 * n + 1] - sw;
            float dot = vh * dh + vw * dw;
            if (dot >= 0.0f && dot <= L2) {
                float cn2 = vh * vh + vw * vw;
                float dist2 = cn2 - (dot * dot) / L2;
                if (dist2 <= 9.0f) ck++;
            }
        }
        bool det = false;
        if (!__any(ck > 0)) {
            // per-sample early-exit: lane resolves when a masked value/m > 0.5
            float t = (float)lane / 63.0f;
            float ch = fminf(fmaxf(sh * t + eh * (1.0f - t), 0.0f), (float)(HH - 1));
            float cw = fminf(fmaxf(sw * t + ew * (1.0f - t), 0.0f), (float)(WW - 1));
            float rh = rintf(ch), rw = rintf(cw);
            float fh = ch - rh, fw = cw - rw;
            float L = sqrtf(L2);
            float nl = L / 724.07734f;
            float th = 0.70710678f + 2.0f * nl;
            float th2 = th * th;

            bool need = true;
            for (int p = 0; p < 29; ++p) {
                if (!__any(need)) break;
                if (need) {
                    float oh = POH[p], ow = POW[p];
                    float ddh = fh - oh, ddw = fw - ow;
                    if (ddh * ddh + ddw * ddw < th2) {
                        int ph = (int)fminf(fmaxf(rh + oh, 0.0f), (float)(HH - 1));
                        int pw = (int)fminf(fmaxf(rw + ow, 0.0f), (float)(WW - 1));
                        // identical to ref's clip(v/m,0,1) > 0.5
                        if (hm[(ph << 9) + pw] / m > 0.5f) need = false;
                    }
                }
            }
            det = !__any(need);   // every lane's exact lmax > 0.5
        }
        if (lane == 0) {
            float val = det ? 1.0f : 0.0f;
            out_lm[i * NJ + j] = val;
            out_lm[j * NJ + i] = val;
        }
    }
}

extern "C" void kernel_launch(void* const* d_in, const int* in_sizes, int n_in,
                              void* d_out, int out_size, void* d_ws, size_t ws_size,
                              hipStream_t stream) {
    const float* junc = (const float*)d_in[0];   // [250,2]
    const float* hm   = (const float*)d_in[1];   // [512,512]
    float* out = (float*)d_out;
    float* out_lm   = out;                      // 62500 floats (0.0/1.0)
    float* out_junc = out + NJ * NJ;            // 500
    float* out_hm   = out + NJ * NJ + 2 * NJ;   // 262144

    unsigned long long* part = (unsigned long long*)d_ws;            // 64*8192 u64 = 4 MB
    unsigned* cnt  = (unsigned*)((char*)d_ws + (size_t)H1BLK * NBINS * 8);        // 8192 u32
    float*    sum  = (float*)((char*)d_ws + (size_t)H1BLK * NBINS * 8 + NBINS*4); // 8192 f32
    float*    max20 = (float*)((char*)d_ws + (size_t)H1BLK * NBINS * 8 + NBINS*8);// 1 f32

    hist_kernel<<<H1BLK, H1THR, 0, stream>>>(hm, part);
    merge_kernel<<<MBLK, MTHR, 0, stream>>>(part, cnt, sum);
    select_kernel<<<1, STHR, 0, stream>>>(cnt, sum, max20);
    main_kernel<<<CBLK, CTHR, 0, stream>>>(junc, hm, max20, out_lm, out_junc, out_hm);
}

// Round 6
// 101.713 us; speedup vs baseline: 2.8014x; 1.1010x over previous
//
#include <hip/hip_runtime.h>
#include <hip/hip_bf16.h>

#define HH 512
#define WW 512
#define NJ 250
#define NBINS 8192
#define NPAIR 31125   // 250*249/2

#define H1BLK 64
#define H1THR 1024
#define MBLK 32
#define MTHR 256
#define STHR 1024
#define CBLK 1024
#define CTHR 256
#define CTOT (CBLK * CTHR)
#define CWAVES (CTOT / 64)

// ---- K1: per-block LDS histogram, ONE packed u64 atomic per valid value.
// packet = (1<<40) | round(v * 2^24); count in bits [40..63], sum in [0..39].
__global__ __launch_bounds__(H1THR) void hist_kernel(const float* __restrict__ hm,
                                                     unsigned long long* __restrict__ part) {
    __shared__ unsigned long long h[NBINS];   // 64 KB
    for (int i = threadIdx.x; i < NBINS; i += H1THR) h[i] = 0ull;
    __syncthreads();

    int idx = blockIdx.x * H1THR + threadIdx.x;     // 65536 threads, 1 float4 each
    float4 v4 = ((const float4*)hm)[idx];
    float vv[4] = {v4.x, v4.y, v4.z, v4.w};
#pragma unroll
    for (int q = 0; q < 4; ++q) {
        float v = vv[q];
        if (v > 0.001f) {
            int b = (int)(v * (float)NBINS);
            b = min(max(b, 0), NBINS - 1);
            unsigned long long pkt = (1ull << 40) |
                (unsigned long long)(unsigned)(v * 16777216.0f + 0.5f);
            atomicAdd(&h[b], pkt);
        }
    }
    __syncthreads();
    for (int i = threadIdx.x; i < NBINS; i += H1THR)
        part[blockIdx.x * NBINS + i] = h[i];
}

// ---- K2: merge 64 partials per bin -> u32 cnt + f32 sum (one thread per bin)
__global__ __launch_bounds__(MTHR) void merge_kernel(const unsigned long long* __restrict__ part,
                                                     unsigned* __restrict__ cnt,
                                                     float* __restrict__ sum) {
    int bin = blockIdx.x * MTHR + threadIdx.x;      // 8192 threads
    unsigned c = 0;
    double s = 0.0;
    for (int p = 0; p < H1BLK; ++p) {
        unsigned long long x = part[p * NBINS + bin];
        c += (unsigned)(x >> 40);
        s += (double)(x & ((1ull << 40) - 1));
    }
    cnt[bin] = c;
    sum[bin] = (float)(s * (1.0 / 16777216.0));
}

// ---- K3: descending prefix scan over bins, top-k boundary -> max20
__global__ __launch_bounds__(STHR) void select_kernel(const unsigned* __restrict__ cnt,
                                                      const float* __restrict__ sum,
                                                      float* __restrict__ max20) {
    __shared__ unsigned sc[STHR];
    __shared__ double   ss[STHR];
    const int t = threadIdx.x;

    unsigned mycnt[8];
    double   mysum[8];
    unsigned c = 0;
    double   s = 0.0;
#pragma unroll
    for (int j = 0; j < 8; ++j) {
        int b = (NBINS - 1) - (t * 8 + j);   // descending bins
        unsigned cb = cnt[b];
        double   sb = (double)sum[b];
        mycnt[j] = cb; mysum[j] = sb;
        c += cb; s += sb;
    }
    sc[t] = c; ss[t] = s;
    __syncthreads();
    for (int off = 1; off < STHR; off <<= 1) {
        unsigned ca = (t >= off) ? sc[t - off] : 0u;
        double   sa = (t >= off) ? ss[t - off] : 0.0;
        __syncthreads();
        sc[t] += ca; ss[t] += sa;
        __syncthreads();
    }
    unsigned incl_c = sc[t];
    double   incl_s = ss[t];
    unsigned excl_c = incl_c - c;
    double   excl_s = incl_s - s;

    unsigned C = sc[STHR - 1];              // total valid count
    int k = (int)ceilf((float)C * 0.2f);    // replicate jnp f32 arithmetic
    if (k <= 0) {
        if (t == 0) *max20 = 0.0f;
        return;
    }
    if (excl_c < (unsigned)k && incl_c >= (unsigned)k) {
        unsigned cum = excl_c;
        double sacc = excl_s;
#pragma unroll
        for (int j = 0; j < 8; ++j) {
            unsigned cb = mycnt[j];
            if (cum + cb >= (unsigned)k) {
                unsigned r = (unsigned)k - cum;
                double partial = cb ? mysum[j] * ((double)r / (double)cb) : 0.0;
                *max20 = (float)((sacc + partial) / (double)k);
                break;
            }
            cum += cb;
            sacc += mysum[j];
        }
    }
}

// ---- K4: refine heatmap + copy junctions + full line_map (0/1 writes)
__global__ __launch_bounds__(CTHR) void main_kernel(const float* __restrict__ junc,
                                                    const float* __restrict__ hm,
                                                    const float* __restrict__ max20p,
                                                    float* __restrict__ out_lm,
                                                    float* __restrict__ out_junc,
                                                    float* __restrict__ out_hm) {
    // patch offsets (circular r<=3), compile-time constants -> folded immediates
    constexpr int IOH[29] = {-3,-2,-2,-2,-2,-2,-1,-1,-1,-1,-1,
                              0, 0, 0, 0, 0, 0, 0,
                              1, 1, 1, 1, 1, 2, 2, 2, 2, 2, 3};
    constexpr int IOW[29] = { 0,-2,-1, 0, 1, 2,-2,-1, 0, 1, 2,
                             -3,-2,-1, 0, 1, 2, 3,
                             -2,-1, 0, 1, 2,-2,-1, 0, 1, 2, 0};

    __shared__ float sj[2 * NJ];
    const int tid  = blockIdx.x * CTHR + threadIdx.x;
    const int lane = threadIdx.x & 63;
    const float m = *max20p;

    for (int i = threadIdx.x; i < 2 * NJ; i += CTHR) sj[i] = junc[i];

    // refined heatmap (one float4 per thread for the first 65536 threads)
    if (tid < HH * WW / 4) {
        const float4* h4 = (const float4*)hm;
        float4* o4 = (float4*)out_hm;
        float4 v = h4[tid];
        float4 r;
        r.x = fminf(fmaxf(v.x / m, 0.0f), 1.0f);
        r.y = fminf(fmaxf(v.y / m, 0.0f), 1.0f);
        r.z = fminf(fmaxf(v.z / m, 0.0f), 1.0f);
        r.w = fminf(fmaxf(v.w / m, 0.0f), 1.0f);
        o4[tid] = r;
    }
    if (tid < 2 * NJ) out_junc[tid] = junc[tid];
    if (tid < NJ) out_lm[tid * (NJ + 1)] = 0.0f;   // diagonal
    __syncthreads();

    // persistent pairs loop: one wave per pair; every pair writes both cells
    const int wave = tid >> 6;
    for (int mm = wave; mm < NPAIR; mm += CWAVES) {
        // decode triangular index: base(i) = i*(499-i)/2 (fixup loops make exact)
        int i = (int)((499.0f - sqrtf(249001.0f - 8.0f * (float)mm)) * 0.5f);
        if (i < 0) i = 0;
        if (i > 248) i = 248;
        while ((i + 1) * (499 - (i + 1)) / 2 <= mm) ++i;
        while (i * (499 - i) / 2 > mm) --i;
        int j = i + 1 + (mm - i * (499 - i) / 2);

        float sh = sj[2 * i], sw = sj[2 * i + 1];
        float eh = sj[2 * j], ew = sj[2 * j + 1];
        float dh = eh - sh, dw = ew - sw;
        float L2 = dh * dh + dw * dw;

        // keep: any other junction on the segment (dist<=3, proj in [0,1])?
        int ck = 0;
        for (int n = lane; n < NJ; n += 64) {
            if (n == i || n == j) continue;
            float vh = sj[2 * n] - sh;
            float vw = sj[2 * n + 1] - sw;
            float dot = vh * dh + vw * dw;
            if (dot >= 0.0f && dot <= L2) {
                float cn2 = vh * vh + vw * vw;
                float dist2 = cn2 - (dot * dot) / L2;
                if (dist2 <= 9.0f) ck++;
            }
        }
        bool det = false;
        if (!__any(ck > 0)) {
            float t = (float)lane / 63.0f;
            float ch = fminf(fmaxf(sh * t + eh * (1.0f - t), 0.0f), (float)(HH - 1));
            float cw = fminf(fmaxf(sw * t + ew * (1.0f - t), 0.0f), (float)(WW - 1));
            float rh = rintf(ch), rw = rintf(cw);
            float fh = ch - rh, fw = cw - rw;
            float L = sqrtf(L2);
            float nl = L / 724.07734f;
            float th = 0.70710678f + 2.0f * nl;
            float th2 = th * th;

            int crh = (int)rh, crw = (int)rw;
            int caddr = (crh << 9) + crw;      // center pixel, always in-range

            // 29 independent loads; invalid points read the center's cache line
            // and are value-masked to 0. No exec divergence -> all loads in flight.
            float best = 0.0f;
#pragma unroll
            for (int p = 0; p < 29; ++p) {
                float ddh = fh - (float)IOH[p];
                float ddw = fw - (float)IOW[p];
                bool valid = (ddh * ddh + ddw * ddw) < th2;
                int ph = min(max(crh + IOH[p], 0), HH - 1);
                int pw = min(max(crw + IOW[p], 0), WW - 1);
                int addr = valid ? ((ph << 9) + pw) : caddr;
                float v = hm[addr];
                best = fmaxf(best, valid ? v : 0.0f);
            }
            // det iff every sample's exact lmax/m > 0.5 (division monotone in m>0)
            det = __all(best / m > 0.5f);
        }
        if (lane == 0) {
            float val = det ? 1.0f : 0.0f;
            out_lm[i * NJ + j] = val;
            out_lm[j * NJ + i] = val;
        }
    }
}

extern "C" void kernel_launch(void* const* d_in, const int* in_sizes, int n_in,
                              void* d_out, int out_size, void* d_ws, size_t ws_size,
                              hipStream_t stream) {
    const float* junc = (const float*)d_in[0];   // [250,2]
    const float* hm   = (const float*)d_in[1];   // [512,512]
    float* out = (float*)d_out;
    float* out_lm   = out;                      // 62500 floats (0.0/1.0)
    float* out_junc = out + NJ * NJ;            // 500
    float* out_hm   = out + NJ * NJ + 2 * NJ;   // 262144

    unsigned long long* part = (unsigned long long*)d_ws;            // 64*8192 u64 = 4 MB
    unsigned* cnt  = (unsigned*)((char*)d_ws + (size_t)H1BLK * NBINS * 8);        // 8192 u32
    float*    sum  = (float*)((char*)d_ws + (size_t)H1BLK * NBINS * 8 + NBINS*4); // 8192 f32
    float*    max20 = (float*)((char*)d_ws + (size_t)H1BLK * NBINS * 8 + NBINS*8);// 1 f32

    hist_kernel<<<H1BLK, H1THR, 0, stream>>>(hm, part);
    merge_kernel<<<MBLK, MTHR, 0, stream>>>(part, cnt, sum);
    select_kernel<<<1, STHR, 0, stream>>>(cnt, sum, max20);
    main_kernel<<<CBLK, CTHR, 0, stream>>>(junc, hm, max20, out_lm, out_junc, out_hm);
}